// Round 1
// 119.148 us; speedup vs baseline: 1.0689x; 1.0689x over previous
//
#include <hip/hip_runtime.h>

// x: [B=16, T=16384, C=64] fp32. bp_sos/lp_sos: [2,6] fp32 rows (b0,b1,b2,a0,a1,a2; a0==1).
#define B_LEN 16
#define T_LEN 16384
#define C_LEN 64
#define CHUNK 64    // output samples per thread; 2x compute amp (warm 64)
#define WARM  64    // zero-state warmup; transient ~0.83^64 ~ 7e-6 (empirically safe: absmax 0.0156)

// R6: latency fix. rocprof R5: VGPR=20, ~870 cyc/sample-step == one HBM miss latency --
// compiler register-minimized and issued loads just-in-time (no MLP), despite unroll-8.
// This version forces a 32-sample register pipeline: 4 named 8-float buffers, each
// reloaded right after consumption, so every load group is issued ~24 samples
// (~1000 issue-cycles) before its use. Occupancy is grid-capped at 16 waves/CU,
// so spending ~70-100 VGPRs is free (<=128 keeps 4 waves/SIMD).
// Arithmetic order in step() is unchanged -> bit-identical output vs R5.
__global__ __launch_bounds__(256) void iir_pipe_kernel(
    const float* __restrict__ x,
    const float* __restrict__ bp,
    const float* __restrict__ lp,
    float* __restrict__ out)
{
    const int c     = threadIdx.x & 63;        // channel within batch
    const int bsub  = threadIdx.x >> 6;        // 0..3
    const int b     = blockIdx.y * 4 + bsub;   // batch 0..15
    const int chunk = blockIdx.x;              // 0..T/CHUNK-1

    // Uniform coefficients -> scalar (SGPR) loads. a's negated so updates are pure FMA.
    const float b10 = bp[0], b11 = bp[1], b12 = bp[2],  a11 = -bp[4],  a12 = -bp[5];
    const float b20 = bp[6], b21 = bp[7], b22 = bp[8],  a21 = -bp[10], a22 = -bp[11];
    const float b30 = lp[0], b31 = lp[1], b32 = lp[2],  a31 = -lp[4],  a32 = -lp[5];
    const float b40 = lp[6], b41 = lp[7], b42 = lp[8],  a41 = -lp[10], a42 = -lp[11];

    const int t_out0 = chunk * CHUNK;
    const int warm   = (t_out0 < WARM) ? t_out0 : WARM;  // 0 (chunk 0) or 64, block-uniform
    const int t0     = t_out0 - warm;

    // DF2T state: 2 per section
    float s11 = 0.f, s12 = 0.f;
    float s21 = 0.f, s22 = 0.f;
    float s31 = 0.f, s32 = 0.f;
    float s41 = 0.f, s42 = 0.f;

    const float* __restrict__ lq = x   + ((size_t)b * T_LEN + t0)     * C_LEN + c;
    float*       __restrict__ po = out + ((size_t)b * T_LEN + t_out0) * C_LEN + c;

    auto step = [&](float xn) -> float {
        // section 1 (bandpass)
        float y1 = fmaf(b10, xn, s11);
        s11 = fmaf(b11, xn, fmaf(a11, y1, s12));
        s12 = fmaf(b12, xn, a12 * y1);
        // section 2 (bandpass)
        float y2 = fmaf(b20, y1, s21);
        s21 = fmaf(b21, y1, fmaf(a21, y2, s22));
        s22 = fmaf(b22, y1, a22 * y2);
        // squaring nonlinearity
        float v = y2 * y2;
        // section 3 (lowpass)
        float y3 = fmaf(b30, v, s31);
        s31 = fmaf(b31, v, fmaf(a31, y3, s32));
        s32 = fmaf(b32, v, a32 * y3);
        // section 4 (lowpass)
        float y4 = fmaf(b40, y3, s41);
        s41 = fmaf(b41, y3, fmaf(a41, y4, s42));
        s42 = fmaf(b42, y3, a42 * y4);
        return y4;
    };

    // 4x8 register pipeline. All indices compile-time after unroll (no scratch).
    float P0[8], P1[8], P2[8], P3[8];

    auto load8 = [&](float* d) {
#pragma unroll
        for (int j = 0; j < 8; ++j) d[j] = lq[j * C_LEN];  // dword + imm offsets off one addr
        lq += 8 * C_LEN;
    };
    auto warm8 = [&](const float* d) {
#pragma unroll
        for (int j = 0; j < 8; ++j) step(d[j]);            // discard outputs
    };
    auto emit8 = [&](const float* d) {
#pragma unroll
        for (int j = 0; j < 8; ++j) {
            float y = step(d[j]);
            __builtin_nontemporal_store(y, po);            // streaming store, never re-read
            po += C_LEN;
        }
    };

    // Prologue: 32 samples in flight before the first dependent FMA.
    load8(P0); load8(P1); load8(P2); load8(P3);

    // Warm phase: warm/32 rotations (0 or 2). Each group reloads +32 samples ahead.
    // Loads issued here cover samples [32, warm+32).
    const int nrot = warm >> 5;
    for (int r = 0; r < nrot; ++r) {
        warm8(P0); load8(P0);
        warm8(P1); load8(P1);
        warm8(P2); load8(P2);
        warm8(P3); load8(P3);
    }
    // Emit part 1: process [warm, warm+32), load [warm+32, warm+64). Last load ends
    // exactly at t0+warm+64 = t_out0+64 <= T: no OOB, no clamp needed.
    emit8(P0); load8(P0);
    emit8(P1); load8(P1);
    emit8(P2); load8(P2);
    emit8(P3); load8(P3);
    // Emit part 2: process [warm+32, warm+64), no further loads.
    emit8(P0);
    emit8(P1);
    emit8(P2);
    emit8(P3);
}

extern "C" void kernel_launch(void* const* d_in, const int* in_sizes, int n_in,
                              void* d_out, int out_size, void* d_ws, size_t ws_size,
                              hipStream_t stream) {
    const float* x  = (const float*)d_in[0];
    const float* bp = (const float*)d_in[1];
    const float* lp = (const float*)d_in[2];
    float* out      = (float*)d_out;

    dim3 grid(T_LEN / CHUNK, B_LEN / 4);   // 256 x 4 = 1024 blocks -> 4 blocks/CU, 16 waves/CU
    dim3 block(256);                        // 4 waves: 4 batches x 64 channels
    iir_pipe_kernel<<<grid, block, 0, stream>>>(x, bp, lp, out);
}